// Round 20
// baseline (340.283 us; speedup 1.0000x reference)
//
#include <hip/hip_runtime.h>
#include <math.h>

// B,C,T = 32,1024,1024; beta=0.95; thr=1.0; sigma=10.5
#define B_     32
#define C_     1024
#define T_     1024
#define RT     92                 // tap radius (|d|>92 cannot flip any f32 spike; r2-r19)
#define CT     64                 // channels per block
#define TTC    32                 // chunk length (time)
#define KC     16                 // channels per thread (halves conv DS vs KC=8)
#define WOFF   (RT + KC - 1)      // 107: tap idx = d + 107, real idx in [15,199]
#define NWT    216                // tap floats (54 quads, in buffer row pads)
#define NCOLS  (CT + 2*RT)        // 248 staged channel columns
#define XSTR   252                // row stride (dwords); cols 248..251 = tap pad
#define ISTR   33                 // strip row stride: conflict-free b32 scan
#define NQ4    (NCOLS * (TTC/4))  // 1984 staged float4s per chunk

// numpy-faithful f32 tap (identical op sequence; exp via correctly-rounded f64).
__device__ __forceinline__ float tap_value(float s, int d) {
    float u    = __fdiv_rn((float)d, s);
    float t1   = __fmul_rn(-0.5f, u);
    float t2   = __fmul_rn(t1, u);
    float e    = (float)exp((double)t2);
    float den  = __fmul_rn(s, sqrtf(6.2831854820251465f));
    float coef = __fdiv_rn(1.0f, den);
    return __fmul_rn(coef, e);
}

#define EL(v, i) ((i) == 0 ? (v).x : (i) == 1 ? (v).y : (i) == 2 ? (v).z : (v).w)
// il in [0,26] -> select from 7 tap quads (compile-time) — v15-verbatim
#define SEL7(il, W0, W1, W2, W3, W4, W5, W6)                                    \
    ((il) < 4 ? EL(W0, (il)) : (il) < 8 ? EL(W1, (il) - 4)                      \
     : (il) < 12 ? EL(W2, (il) - 8) : (il) < 16 ? EL(W3, (il) - 12)             \
     : (il) < 20 ? EL(W4, (il) - 16) : (il) < 24 ? EL(W5, (il) - 20)            \
     : EL(W6, (il) - 24))

// One source column (pass-relative cc): 16 FMAs, taps compile-time selected.
#define COL16(XV, CC, W0, W1, W2, W3, W4, W5, W6)                               \
    do {                                                                        \
        float x1_ = EL(XV, (CC) & 3);                                           \
        _Pragma("unroll")                                                       \
        for (int k = 0; k < KC; ++k) {                                          \
            const int il_ = (CC) + (KC - 1) - k;                                \
            acc[k] = fmaf(SEL7(il_, W0, W1, W2, W3, W4, W5, W6), x1_, acc[k]);  \
        }                                                                       \
    } while (0)

// Tap quad Q (compile-time 0..53): quads 0..31 in xsA row pads, 32..53 in xsB.
#define TAPQ(Q)                                                                 \
    (*(const float4*)(((Q) < 32 ? xsA + (Q) * XSTR : xsB + ((Q) - 32) * XSTR) + 248))

// Pass p: cols 12p..12p+11 (ascending j), tap quads 3p..3p+6, x quads 3p..3p+2.
#define PASS(P)                                                                 \
    do {                                                                        \
        float4 w0 = TAPQ(3*(P)+0), w1 = TAPQ(3*(P)+1), w2 = TAPQ(3*(P)+2);      \
        float4 w3 = TAPQ(3*(P)+3), w4 = TAPQ(3*(P)+4), w5 = TAPQ(3*(P)+5);      \
        float4 w6 = TAPQ(3*(P)+6);                                              \
        float4 a0 = xq[3*(P)+0], a1 = xq[3*(P)+1], a2 = xq[3*(P)+2];            \
        COL16(a0, 0,  w0,w1,w2,w3,w4,w5,w6); COL16(a0, 1,  w0,w1,w2,w3,w4,w5,w6); \
        COL16(a0, 2,  w0,w1,w2,w3,w4,w5,w6); COL16(a0, 3,  w0,w1,w2,w3,w4,w5,w6); \
        COL16(a1, 4,  w0,w1,w2,w3,w4,w5,w6); COL16(a1, 5,  w0,w1,w2,w3,w4,w5,w6); \
        COL16(a1, 6,  w0,w1,w2,w3,w4,w5,w6); COL16(a1, 7,  w0,w1,w2,w3,w4,w5,w6); \
        COL16(a2, 8,  w0,w1,w2,w3,w4,w5,w6); COL16(a2, 9,  w0,w1,w2,w3,w4,w5,w6); \
        COL16(a2, 10, w0,w1,w2,w3,w4,w5,w6); COL16(a2, 11, w0,w1,w2,w3,w4,w5,w6); \
    } while (0)

// Last pass: cols 192..199, tap quads 48..53 (il <= 22), x quads 48..49.
#define PASSL()                                                                 \
    do {                                                                        \
        float4 w0 = TAPQ(48), w1 = TAPQ(49), w2 = TAPQ(50);                     \
        float4 w3 = TAPQ(51), w4 = TAPQ(52), w5 = TAPQ(53);                     \
        float4 a0 = xq[48], a1 = xq[49];                                        \
        COL16(a0, 0, w0,w1,w2,w3,w4,w5,w5); COL16(a0, 1, w0,w1,w2,w3,w4,w5,w5); \
        COL16(a0, 2, w0,w1,w2,w3,w4,w5,w5); COL16(a0, 3, w0,w1,w2,w3,w4,w5,w5); \
        COL16(a1, 4, w0,w1,w2,w3,w4,w5,w5); COL16(a1, 5, w0,w1,w2,w3,w4,w5,w5); \
        COL16(a1, 6, w0,w1,w2,w3,w4,w5,w5); COL16(a1, 7, w0,w1,w2,w3,w4,w5,w5); \
    } while (0)

// 4-wave (256-thr) blocks: VGPR unpins to ~108 (v15 counter-evidence), so the
// KC=16 conv holds its operands in registers. Parity role-split (r19's win):
// group g = chunks of parity g. Step m: group (m&1)'s 2 waves conv chunk m
// (KC=16, 64ch x 32t); other group: wave0 scans chunk m-1, wave1 stages m+1.
__global__ __launch_bounds__(256) void snn_v20(
    const float* __restrict__ x, const float* __restrict__ sigma,
    float* __restrict__ out)
{
    __shared__ __align__(16) float xsA[TTC * XSTR];   // 32256 B (+ tap pads)
    __shared__ __align__(16) float xsB[TTC * XSTR];   // 32256 B (+ tap pads)
    __shared__ __align__(16) float stripA[CT * ISTR]; //  8448 B
    __shared__ __align__(16) float stripB[CT * ISTR]; //  8448 B
    __shared__ float mem_lds[CT];                     //   256 B (total 81664)

    const int tx   = threadIdx.x;       // lane 0..63
    const int ty   = threadIdx.y;       // wave 0..3
    const int flat = ty * 64 + tx;
    const int g    = ty >> 1;           // group: 0 = even chunks, 1 = odd
    const int wg   = ty & 1;            // wave within group
    const int b    = blockIdx.y;
    const int c0   = blockIdx.x * CT;

    const float* xb = x   + (size_t)b * ((size_t)C_ * T_);
    float*       ob = out + (size_t)b * ((size_t)C_ * T_);

    // ---- prologue: taps into buf pads, mem init, stage chunk 0 -> xsA ----
    if (flat < NWT) {
        int d = flat - WOFF;
        float w = (d >= -RT && d <= RT) ? tap_value(sigma[0], d) : 0.0f;
        int q = flat >> 2, e = flat & 3;
        float* dst = (q < 32) ? (xsA + q * XSTR + 248 + e)
                              : (xsB + (q - 32) * XSTR + 248 + e);
        *dst = w;
    }
    if (flat < CT) mem_lds[flat] = 0.0f;
#pragma unroll
    for (int i = 0; i < 8; ++i) {       // 1984 quads / 256 threads
        int e = flat + i * 256;
        if (e < NQ4) {
            int r = e >> 3, c4 = e & 7;
            int c = c0 - RT + r;
            float4 v = make_float4(0.f, 0.f, 0.f, 0.f);
            if (c >= 0 && c < C_)
                v = *(const float4*)(xb + (size_t)c * T_ + c4 * 4);
            xsA[(4 * c4 + 0) * XSTR + r] = v.x;
            xsA[(4 * c4 + 1) * XSTR + r] = v.y;
            xsA[(4 * c4 + 2) * XSTR + r] = v.z;
            xsA[(4 * c4 + 3) * XSTR + r] = v.w;
        }
    }
    __syncthreads();

    const int tloc = tx & 31;                   // conv: time lane
    const int rb   = ((tx >> 5) + 2 * wg) * 16; // conv: first channel (wave wg: 32wg..32wg+31)
    float* bufg    = (g == 0) ? xsA : xsB;
    float* stripg  = (g == 0) ? stripA : stripB;
    const float4* xq = (const float4*)(bufg + tloc * XSTR + rb);

#pragma unroll 1
    for (int m = 0; m <= 32; ++m) {
        if (m <= 31 && g == (m & 1)) {
            // ========== CONV chunk m (both waves of my group; KC=16) ==========
            float acc[KC];
#pragma unroll
            for (int k = 0; k < KC; ++k) acc[k] = 0.0f;

            PASS(0);  PASS(1);  PASS(2);  PASS(3);
            PASS(4);  PASS(5);  PASS(6);  PASS(7);
            PASS(8);  PASS(9);  PASS(10); PASS(11);
            PASS(12); PASS(13); PASS(14); PASS(15);
            PASSL();                 // ascending j, exact f32 chain per output

            // I = x - conv -> group strip [ch][t] (own x = cols rb+92..rb+107)
            {
                float4 xo0 = xq[23], xo1 = xq[24], xo2 = xq[25], xo3 = xq[26];
                stripg[(rb +  0) * ISTR + tloc] = __fsub_rn(xo0.x, acc[0]);
                stripg[(rb +  1) * ISTR + tloc] = __fsub_rn(xo0.y, acc[1]);
                stripg[(rb +  2) * ISTR + tloc] = __fsub_rn(xo0.z, acc[2]);
                stripg[(rb +  3) * ISTR + tloc] = __fsub_rn(xo0.w, acc[3]);
                stripg[(rb +  4) * ISTR + tloc] = __fsub_rn(xo1.x, acc[4]);
                stripg[(rb +  5) * ISTR + tloc] = __fsub_rn(xo1.y, acc[5]);
                stripg[(rb +  6) * ISTR + tloc] = __fsub_rn(xo1.z, acc[6]);
                stripg[(rb +  7) * ISTR + tloc] = __fsub_rn(xo1.w, acc[7]);
                stripg[(rb +  8) * ISTR + tloc] = __fsub_rn(xo2.x, acc[8]);
                stripg[(rb +  9) * ISTR + tloc] = __fsub_rn(xo2.y, acc[9]);
                stripg[(rb + 10) * ISTR + tloc] = __fsub_rn(xo2.z, acc[10]);
                stripg[(rb + 11) * ISTR + tloc] = __fsub_rn(xo2.w, acc[11]);
                stripg[(rb + 12) * ISTR + tloc] = __fsub_rn(xo3.x, acc[12]);
                stripg[(rb + 13) * ISTR + tloc] = __fsub_rn(xo3.y, acc[13]);
                stripg[(rb + 14) * ISTR + tloc] = __fsub_rn(xo3.z, acc[14]);
                stripg[(rb + 15) * ISTR + tloc] = __fsub_rn(xo3.w, acc[15]);
            }
        } else if (m <= 32 && g != (m & 1)) {
            if (wg == 0) {
                // ===== SCAN chunk m-1 (my group's strip; lane = channel) =====
                // reset r = (stored mem > 1) == last spike (bit-exact identity).
                if (m >= 1) {
                    float mv = mem_lds[tx];
                    float r  = (mv > 1.0f) ? 1.0f : 0.0f;
                    const float* srow = stripg + tx * ISTR;
                    float* orow = ob + (size_t)(c0 + tx) * T_ + (size_t)(m - 1) * TTC;
#pragma unroll
                    for (int q = 0; q < TTC / 4; ++q) {
                        float4 s;
#pragma unroll
                        for (int qq = 0; qq < 4; ++qq) {
                            float Ivv = srow[4 * q + qq];
                            mv = __fsub_rn(__fadd_rn(__fmul_rn(0.95f, mv), Ivv), r);
                            float sp = (mv > 1.0f) ? 1.0f : 0.0f;
                            r = sp;
                            if (qq == 0) s.x = sp; else if (qq == 1) s.y = sp;
                            else if (qq == 2) s.z = sp; else s.w = sp;
                        }
                        *(float4*)(orow + 4 * q) = s;
                    }
                    mem_lds[tx] = mv;
                }
            } else {
                // ===== STAGE chunk m+1 into my group's buffer (64 lanes) =====
                if (m + 1 <= 31) {
                    const int t0s = (m + 1) * TTC;
                    const int r0  = tx >> 3, c40 = tx & 7;
                    const int cb  = c0 - RT + r0;
#pragma unroll
                    for (int i = 0; i < 31; ++i) {      // 31*64 = 1984 exact
                        int c = cb + 8 * i;
                        float4 v = make_float4(0.f, 0.f, 0.f, 0.f);
                        if (c >= 0 && c < C_)
                            v = *(const float4*)(xb + (size_t)c * T_ + t0s + c40 * 4);
                        int ra = r0 + 8 * i;
                        bufg[(4 * c40 + 0) * XSTR + ra] = v.x;
                        bufg[(4 * c40 + 1) * XSTR + ra] = v.y;
                        bufg[(4 * c40 + 2) * XSTR + ra] = v.z;
                        bufg[(4 * c40 + 3) * XSTR + ra] = v.w;
                    }
                }
            }
        }
        __syncthreads();    // step boundary: buffer/strip/mem handoff ordered
    }
}

extern "C" void kernel_launch(void* const* d_in, const int* in_sizes, int n_in,
                              void* d_out, int out_size, void* d_ws, size_t ws_size,
                              hipStream_t stream) {
    const float* x     = (const float*)d_in[0];   // [32,1024,1024] f32
    const float* sigma = (const float*)d_in[1];   // [1] f32
    float* out = (float*)d_out;

    dim3 grid(C_ / CT, B_);   // (16, 32) = 512 blocks, 2/CU
    dim3 block(64, 4);        // 256 threads, 4 waves (A: 0-1, B: 2-3)

    snn_v20<<<grid, block, 0, stream>>>(x, sigma, out);
}